// Round 1
// baseline (3514.671 us; speedup 1.0000x reference)
//
#include <hip/hip_runtime.h>
#include <cstddef>
#include <cstdint>

#define BATCH  2
#define SEQ    2048
#define DMODEL 1024
#define NHEAD  16
#define HDIM   64
#define SCALE  0.125f

// ---------------------------------------------------------------------------
// GEMM: C = A @ W^T + bias.  A:[M x K] rm, W:[N x K] rm.
// mode 0: N=3072, split cols into d0/d1/d2 (Q/K/V) each [M x 1024]
// mode 1: N=1024, write d0[row*1024+col]
// BM=BN=64, BK=16, 256 threads, 4x4 microtile.
// ---------------------------------------------------------------------------
__global__ __launch_bounds__(256)
void gemm_bias_kernel(const float* __restrict__ A, const float* __restrict__ W,
                      const float* __restrict__ bias,
                      float* __restrict__ d0, float* __restrict__ d1, float* __restrict__ d2,
                      int K, int mode)
{
    __shared__ float As[16][68];
    __shared__ float Bs[16][68];
    int tid = threadIdx.x;
    int tx = tid & 15, ty = tid >> 4;
    int row0 = blockIdx.y * 64, col0 = blockIdx.x * 64;
    int la_row = tid >> 2, la_k = (tid & 3) * 4;
    float acc[4][4] = {};

    for (int k0 = 0; k0 < K; k0 += 16) {
        float4 a4 = *(const float4*)&A[(size_t)(row0 + la_row) * K + k0 + la_k];
        float4 b4 = *(const float4*)&W[(size_t)(col0 + la_row) * K + k0 + la_k];
        __syncthreads();
        As[la_k+0][la_row] = a4.x; As[la_k+1][la_row] = a4.y;
        As[la_k+2][la_row] = a4.z; As[la_k+3][la_row] = a4.w;
        Bs[la_k+0][la_row] = b4.x; Bs[la_k+1][la_row] = b4.y;
        Bs[la_k+2][la_row] = b4.z; Bs[la_k+3][la_row] = b4.w;
        __syncthreads();
        #pragma unroll
        for (int kk = 0; kk < 16; ++kk) {
            float4 av = *(const float4*)&As[kk][ty * 4];
            float4 bv = *(const float4*)&Bs[kk][tx * 4];
            float a_[4] = {av.x, av.y, av.z, av.w};
            float b_[4] = {bv.x, bv.y, bv.z, bv.w};
            #pragma unroll
            for (int ii = 0; ii < 4; ++ii)
                #pragma unroll
                for (int jj = 0; jj < 4; ++jj)
                    acc[ii][jj] += a_[ii] * b_[jj];
        }
    }

    #pragma unroll
    for (int ii = 0; ii < 4; ++ii) {
        int row = row0 + ty * 4 + ii;
        #pragma unroll
        for (int jj = 0; jj < 4; ++jj) {
            int col = col0 + tx * 4 + jj;
            float v = acc[ii][jj] + bias[col];
            if (mode == 0) {
                int sel = col >> 10, c = col & 1023;
                float* dst = (sel == 0) ? d0 : ((sel == 1) ? d1 : d2);
                dst[(size_t)row * DMODEL + c] = v;
            } else {
                d0[(size_t)row * DMODEL + col] = v;
            }
        }
    }
}

// ---------------------------------------------------------------------------
// RoPE applied in-place to Q and K ([B*SEQ][DMODEL] layout).
// One thread per (which, row, head, t) pair; pairs (t, t+32) within head.
// ---------------------------------------------------------------------------
__global__ __launch_bounds__(256)
void rope_kernel(float* __restrict__ Q, float* __restrict__ Kb)
{
    int gid = blockIdx.x * 256 + threadIdx.x;
    int t     = gid & 31;
    int h     = (gid >> 5) & 15;
    int row   = (gid >> 9) & (BATCH * SEQ - 1);
    int which = gid >> 21;
    float* buf = which ? Kb : Q;
    int pos = row & (SEQ - 1);
    float inv = 1.0f / powf(10000.0f, (float)(2 * t) * (1.0f / 64.0f));
    float ang = (float)pos * inv;
    float c = cosf(ang), s = sinf(ang);
    size_t base = (size_t)row * DMODEL + h * HDIM + t;
    float x1 = buf[base], x2 = buf[base + 32];
    buf[base]      = x1 * c - x2 * s;
    buf[base + 32] = x1 * s + x2 * c;
}

// ---------------------------------------------------------------------------
// Pass A: per-row (m, Z) of pre-mixed logits S'_g = SCALE * sum_h Wpre[g,h] q_h.k_h
// Block: (b, 8 query rows), 256 threads. Flash-style over all 2048 keys.
// ---------------------------------------------------------------------------
__global__ __launch_bounds__(256)
void attn_stats_kernel(const float* __restrict__ Q, const float* __restrict__ Kb,
                       const float* __restrict__ Wpre,
                       float* __restrict__ Mrow, float* __restrict__ Zrow)
{
    __shared__ float Qs[8 * 1032];
    __shared__ float Ks[8 * 1032];
    __shared__ float Ss[16 * 64];
    __shared__ float wpre[256];
    int tid = threadIdx.x;
    int b  = blockIdx.x >> 8;
    int i0 = (blockIdx.x & 255) * 8;

    wpre[tid] = Wpre[tid];
    #pragma unroll
    for (int v = 0; v < 8; ++v) {
        int lin = v * 256 + tid;
        int r = lin >> 8, c4 = (lin & 255) * 4;
        *(float4*)&Qs[r * 1032 + c4] =
            *(const float4*)&Q[(size_t)(b * SEQ + i0 + r) * DMODEL + c4];
    }

    float m_run = -INFINITY, z_run = 0.f;
    int g = tid >> 3, ii = tid & 7;

    for (int j0 = 0; j0 < SEQ; j0 += 8) {
        #pragma unroll
        for (int v = 0; v < 8; ++v) {
            int lin = v * 256 + tid;
            int r = lin >> 8, c4 = (lin & 255) * 4;
            *(float4*)&Ks[r * 1032 + c4] =
                *(const float4*)&Kb[(size_t)(b * SEQ + j0 + r) * DMODEL + c4];
        }
        __syncthreads();
        #pragma unroll
        for (int rr = 0; rr < 4; ++rr) {
            int h = rr * 4 + (tid >> 6);
            int lane = tid & 63;
            int pi = lane >> 3, pj = lane & 7;
            const float* qp = &Qs[pi * 1032 + h * 64];
            const float* kp = &Ks[pj * 1032 + h * 64];
            float acc = 0.f;
            #pragma unroll
            for (int d = 0; d < 64; d += 4) {
                float4 q4 = *(const float4*)(qp + d);
                float4 k4 = *(const float4*)(kp + d);
                acc += q4.x * k4.x + q4.y * k4.y + q4.z * k4.z + q4.w * k4.w;
            }
            Ss[h * 64 + pi * 8 + pj] = acc;
        }
        __syncthreads();
        if (tid < 128) {
            #pragma unroll
            for (int j = 0; j < 8; ++j) {
                float s = 0.f;
                #pragma unroll
                for (int h = 0; h < 16; ++h)
                    s += wpre[g * 16 + h] * Ss[h * 64 + ii * 8 + j];
                s *= SCALE;
                float mo = m_run;
                m_run = fmaxf(m_run, s);
                z_run = z_run * __expf(mo - m_run) + __expf(s - m_run);
            }
        }
    }
    if (tid < 128) {
        size_t idx = (size_t)(b * NHEAD + g) * SEQ + i0 + ii;
        Mrow[idx] = m_run;
        Zrow[idx] = z_run;
    }
}

// ---------------------------------------------------------------------------
// Pass B: recompute S', normalize per (g,i) with (m,Z), post-mix Wpost,
// accumulate attn2 @ V into CTX ([b,n,dim] layout).
// ---------------------------------------------------------------------------
__global__ __launch_bounds__(256)
void attn_apply_kernel(const float* __restrict__ Q, const float* __restrict__ Kb,
                       const float* __restrict__ V,
                       const float* __restrict__ Wpre, const float* __restrict__ Wpost,
                       const float* __restrict__ Mrow, const float* __restrict__ Zrow,
                       float* __restrict__ CTX)
{
    __shared__ float Qs[8 * 1032];
    __shared__ float Ks[8 * 1032];
    __shared__ float Ss[16 * 64];
    __shared__ float Es[16 * 64];
    __shared__ float wpre[256];
    __shared__ float wpost[256];
    __shared__ float mrow[128];
    __shared__ float zin[128];
    int tid = threadIdx.x;
    int b  = blockIdx.x >> 8;
    int i0 = (blockIdx.x & 255) * 8;

    wpre[tid] = Wpre[tid];
    wpost[tid] = Wpost[tid];
    #pragma unroll
    for (int v = 0; v < 8; ++v) {
        int lin = v * 256 + tid;
        int r = lin >> 8, c4 = (lin & 255) * 4;
        *(float4*)&Qs[r * 1032 + c4] =
            *(const float4*)&Q[(size_t)(b * SEQ + i0 + r) * DMODEL + c4];
    }
    int g = tid >> 3, ii = tid & 7;           // roles for phase2 (tid<128)
    if (tid < 128) {
        size_t idx = (size_t)(b * NHEAD + g) * SEQ + i0 + ii;
        mrow[tid] = Mrow[idx];
        zin[tid]  = 1.0f / Zrow[idx];
    }
    int po = tid >> 1;
    int ga = po >> 3, ia = po & 7, half = tid & 1;  // roles for phase3
    float o[32] = {};

    for (int j0 = 0; j0 < SEQ; j0 += 8) {
        #pragma unroll
        for (int v = 0; v < 8; ++v) {
            int lin = v * 256 + tid;
            int r = lin >> 8, c4 = (lin & 255) * 4;
            *(float4*)&Ks[r * 1032 + c4] =
                *(const float4*)&Kb[(size_t)(b * SEQ + j0 + r) * DMODEL + c4];
        }
        __syncthreads();
        #pragma unroll
        for (int rr = 0; rr < 4; ++rr) {
            int h = rr * 4 + (tid >> 6);
            int lane = tid & 63;
            int pi = lane >> 3, pj = lane & 7;
            const float* qp = &Qs[pi * 1032 + h * 64];
            const float* kp = &Ks[pj * 1032 + h * 64];
            float acc = 0.f;
            #pragma unroll
            for (int d = 0; d < 64; d += 4) {
                float4 q4 = *(const float4*)(qp + d);
                float4 k4 = *(const float4*)(kp + d);
                acc += q4.x * k4.x + q4.y * k4.y + q4.z * k4.z + q4.w * k4.w;
            }
            Ss[h * 64 + pi * 8 + pj] = acc;
        }
        __syncthreads();
        if (tid < 128) {
            #pragma unroll
            for (int j = 0; j < 8; ++j) {
                float s = 0.f;
                #pragma unroll
                for (int h = 0; h < 16; ++h)
                    s += wpre[g * 16 + h] * Ss[h * 64 + ii * 8 + j];
                s *= SCALE;
                Es[g * 64 + ii * 8 + j] = __expf(s - mrow[tid]) * zin[tid];
            }
        }
        __syncthreads();
        #pragma unroll
        for (int j = 0; j < 8; ++j) {
            float w2 = 0.f;
            #pragma unroll
            for (int h = 0; h < 16; ++h)
                w2 += wpost[ga * 16 + h] * Es[h * 64 + ia * 8 + j];
            const float* vrow = &V[(size_t)(b * SEQ + j0 + j) * DMODEL + ga * 64 + half * 32];
            #pragma unroll
            for (int d4 = 0; d4 < 8; ++d4) {
                float4 v4 = *(const float4*)(vrow + d4 * 4);
                o[d4 * 4 + 0] += w2 * v4.x;
                o[d4 * 4 + 1] += w2 * v4.y;
                o[d4 * 4 + 2] += w2 * v4.z;
                o[d4 * 4 + 3] += w2 * v4.w;
            }
        }
    }

    float* dst = &CTX[(size_t)(b * SEQ + i0 + ia) * DMODEL + ga * 64 + half * 32];
    #pragma unroll
    for (int d4 = 0; d4 < 8; ++d4) {
        *(float4*)(dst + d4 * 4) =
            make_float4(o[d4*4+0], o[d4*4+1], o[d4*4+2], o[d4*4+3]);
    }
}

// ---------------------------------------------------------------------------
extern "C" void kernel_launch(void* const* d_in, const int* in_sizes, int n_in,
                              void* d_out, int out_size, void* d_ws, size_t ws_size,
                              hipStream_t stream)
{
    const float* x     = (const float*)d_in[0];
    const float* Wqkv  = (const float*)d_in[1];
    const float* bqkv  = (const float*)d_in[2];
    const float* Wpre  = (const float*)d_in[3];
    const float* Wpost = (const float*)d_in[4];
    const float* Wout  = (const float*)d_in[5];
    const float* bout  = (const float*)d_in[6];
    float* out = (float*)d_out;

    float* ws   = (float*)d_ws;
    float* Qb   = ws;                       // [4096][1024]
    float* Kb   = ws + 4194304;             // [4096][1024]
    float* Vb   = ws + 8388608;             // [4096][1024]
    float* CTX  = ws + 12582912;            // [4096][1024]
    float* Mrow = ws + 16777216;            // [2*16*2048]
    float* Zrow = Mrow + 65536;

    dim3 blk(256);
    gemm_bias_kernel<<<dim3(48, 64), blk, 0, stream>>>(x, Wqkv, bqkv, Qb, Kb, Vb, 1024, 0);
    rope_kernel<<<16384, blk, 0, stream>>>(Qb, Kb);
    attn_stats_kernel<<<512, blk, 0, stream>>>(Qb, Kb, Wpre, Mrow, Zrow);
    attn_apply_kernel<<<512, blk, 0, stream>>>(Qb, Kb, Vb, Wpre, Wpost, Mrow, Zrow, CTX);
    gemm_bias_kernel<<<dim3(16, 64), blk, 0, stream>>>(CTX, Wout, bout, out, nullptr, nullptr, 1024, 1);
}

// Round 2
// 732.184 us; speedup vs baseline: 4.8003x; 4.8003x over previous
//
#include <hip/hip_runtime.h>
#include <cstddef>
#include <cstdint>

#define SEQ    2048
#define DMODEL 1024
#define NHEAD  16
#define HDIM   64
#define SCALE  0.125f

typedef _Float16 f16;
typedef unsigned short u16;
typedef unsigned int   u32;
typedef __attribute__((ext_vector_type(8))) _Float16 h8v;
typedef __attribute__((ext_vector_type(4))) _Float16 h4v;
typedef __attribute__((ext_vector_type(4))) float    f4v;

__device__ __forceinline__ u32 pkh(float a, float b) {
    u16 x = __builtin_bit_cast(u16, (f16)a);
    u16 y = __builtin_bit_cast(u16, (f16)b);
    return (u32)x | ((u32)y << 16);
}

__device__ __forceinline__ f4v mfma32(h8v a, h8v b, f4v c) {
    return __builtin_amdgcn_mfma_f32_16x16x32_f16(a, b, c, 0, 0, 0);
}
__device__ __forceinline__ f4v mfma16(h4v a, h4v b, f4v c) {
    return __builtin_amdgcn_mfma_f32_16x16x16f16(a, b, c, 0, 0, 0);
}

// swizzled byte address into ss: logical (pt in [0,512), off in [0,64))
// bijective: f(pt) constant within each even/odd pt pair (128B block)
__device__ __forceinline__ int ssp(int pt, int off) {
    return (pt*64 + off) ^ (((pt>>4)&15)<<3) ^ ((pt&12)<<1);
}

// ---------------------------------------------------------------------------
// fp32 GEMM: C = (A [+A2]) @ W^T + bias. A:[M x K] rm, W:[N x K] rm.
// mode 0: N=3072 -> split into d0/d1/d2. mode 1: N=1024 -> d0.
// ---------------------------------------------------------------------------
__global__ __launch_bounds__(256)
void gemm_bias_kernel(const float* __restrict__ A, const float* __restrict__ A2,
                      const float* __restrict__ W, const float* __restrict__ bias,
                      float* __restrict__ d0, float* __restrict__ d1, float* __restrict__ d2,
                      int K, int mode)
{
    __shared__ float As[16][68];
    __shared__ float Bs[16][68];
    int tid = threadIdx.x;
    int tx = tid & 15, ty = tid >> 4;
    int row0 = blockIdx.y * 64, col0 = blockIdx.x * 64;
    int la_row = tid >> 2, la_k = (tid & 3) * 4;
    float acc[4][4] = {};

    for (int k0 = 0; k0 < K; k0 += 16) {
        float4 a4 = *(const float4*)&A[(size_t)(row0 + la_row) * K + k0 + la_k];
        if (A2) {
            float4 x = *(const float4*)&A2[(size_t)(row0 + la_row) * K + k0 + la_k];
            a4.x += x.x; a4.y += x.y; a4.z += x.z; a4.w += x.w;
        }
        float4 b4 = *(const float4*)&W[(size_t)(col0 + la_row) * K + k0 + la_k];
        __syncthreads();
        As[la_k+0][la_row] = a4.x; As[la_k+1][la_row] = a4.y;
        As[la_k+2][la_row] = a4.z; As[la_k+3][la_row] = a4.w;
        Bs[la_k+0][la_row] = b4.x; Bs[la_k+1][la_row] = b4.y;
        Bs[la_k+2][la_row] = b4.z; Bs[la_k+3][la_row] = b4.w;
        __syncthreads();
        #pragma unroll
        for (int kk = 0; kk < 16; ++kk) {
            float4 av = *(const float4*)&As[kk][ty * 4];
            float4 bv = *(const float4*)&Bs[kk][tx * 4];
            float a_[4] = {av.x, av.y, av.z, av.w};
            float b_[4] = {bv.x, bv.y, bv.z, bv.w};
            #pragma unroll
            for (int ii = 0; ii < 4; ++ii)
                #pragma unroll
                for (int jj = 0; jj < 4; ++jj)
                    acc[ii][jj] += a_[ii] * b_[jj];
        }
    }

    #pragma unroll
    for (int ii = 0; ii < 4; ++ii) {
        int row = row0 + ty * 4 + ii;
        #pragma unroll
        for (int jj = 0; jj < 4; ++jj) {
            int col = col0 + tx * 4 + jj;
            float v = acc[ii][jj] + bias[col];
            if (mode == 0) {
                int sel = col >> 10, c = col & 1023;
                float* dst = (sel == 0) ? d0 : ((sel == 1) ? d1 : d2);
                dst[(size_t)row * DMODEL + c] = v;
            } else {
                d0[(size_t)row * DMODEL + col] = v;
            }
        }
    }
}

// ---------------------------------------------------------------------------
// Pack Q,K (with RoPE) from fp32 [row][1024] into f16 MFMA-frag layout:
//   off = (((((b*128+it)*16+h)*2+ks)*4+c)*16+i)*8 + e   (d = ks*32 + c*8 + e)
// ---------------------------------------------------------------------------
__global__ __launch_bounds__(256)
void pack_qk_kernel(const float* __restrict__ Qb, const float* __restrict__ Kb,
                    f16* __restrict__ Qh, f16* __restrict__ Kh)
{
    int gid = blockIdx.x * 256 + threadIdx.x;
    int i     = gid & 15;
    int t8    = (gid >> 4) & 3;
    int h     = (gid >> 6) & 15;
    int rh    = (gid >> 10) & 255;
    int which = (gid >> 18) & 1;
    int row = rh * 16 + i;
    int pos = row & (SEQ - 1);
    int b   = row >> 11;
    const float* src = which ? Kb : Qb;
    f16* dst = which ? Kh : Qh;

    float y1[8], y2[8];
    #pragma unroll
    for (int e = 0; e < 8; ++e) {
        int t = t8 * 8 + e;
        float x1 = src[(size_t)row * DMODEL + h * 64 + t];
        float x2 = src[(size_t)row * DMODEL + h * 64 + t + 32];
        float inv = powf(10000.0f, -(float)(2 * t) / 64.0f);
        float ang = (float)pos * inv;
        float c = cosf(ang), s = sinf(ang);
        y1[e] = x1 * c - x2 * s;
        y2[e] = x1 * s + x2 * c;
    }
    int it = pos >> 4;
    size_t b0 = (((((size_t)(b*128 + it)*16 + h)*2 + 0)*4 + t8)*16 + i)*8;
    size_t b1 = (((((size_t)(b*128 + it)*16 + h)*2 + 1)*4 + t8)*16 + i)*8;
    uint4 o0, o1;
    o0.x = pkh(y1[0], y1[1]); o0.y = pkh(y1[2], y1[3]);
    o0.z = pkh(y1[4], y1[5]); o0.w = pkh(y1[6], y1[7]);
    o1.x = pkh(y2[0], y2[1]); o1.y = pkh(y2[2], y2[3]);
    o1.z = pkh(y2[4], y2[5]); o1.w = pkh(y2[6], y2[7]);
    *(uint4*)(dst + b0) = o0;
    *(uint4*)(dst + b1) = o1;
}

// ---------------------------------------------------------------------------
// Pack V into f16 PV B-frag layout:
//   off = ((((((b*64+jt)*16+g)*4+dt)*4+jc)*16+dd)*8 + e   (j = jt*32+jc*8+e, d = g*64+dt*16+dd)
// ---------------------------------------------------------------------------
__global__ __launch_bounds__(256)
void pack_v_kernel(const float* __restrict__ Vb, f16* __restrict__ Vt)
{
    int gid = blockIdx.x * 256 + threadIdx.x;
    int dd = gid & 15;
    int jc = (gid >> 4) & 3;
    int dt = (gid >> 6) & 3;
    int g  = (gid >> 8) & 15;
    int jt = (gid >> 12) & 63;
    int b  = (gid >> 18) & 1;
    int d = g * 64 + dt * 16 + dd;
    float v[8];
    #pragma unroll
    for (int e = 0; e < 8; ++e) {
        int j = jt * 32 + jc * 8 + e;
        v[e] = Vb[(size_t)(b * SEQ + j) * DMODEL + d];
    }
    size_t off = ((((((size_t)b*64 + jt)*16 + g)*4 + dt)*4 + jc)*16 + dd)*8;
    uint4 o;
    o.x = pkh(v[0], v[1]); o.y = pkh(v[2], v[3]);
    o.z = pkh(v[4], v[5]); o.w = pkh(v[6], v[7]);
    *(uint4*)(Vt + off) = o;
}

// ---------------------------------------------------------------------------
// MFMA talking-heads attention core.
// FULL=0: pass 1 -> Z partials.  FULL=1: pass 2 -> CTX partials.
// Block: (split, b, it). 256 threads = 4 waves. j-loop over split's 1024 keys, 32/step.
// ---------------------------------------------------------------------------
template<int FULL>
__global__ __launch_bounds__(256, 2)
void attn_core(const f16* __restrict__ Qh, const f16* __restrict__ Kh,
               const f16* __restrict__ Vt, const float* __restrict__ Wpre,
               const float* __restrict__ Wpost, const float* __restrict__ Zp,
               float* __restrict__ Zout, float* __restrict__ Octx)
{
    __shared__ __align__(16) char ss[512 * 64];            // f16 S0 [pt][h32], swizzled, h>=16 zero
    __shared__ __align__(16) char es[FULL ? 16 * 1024 : 16]; // f16 A2 [g'][i][j32], swizzled
    __shared__ float zred[1024];

    int tid = threadIdx.x;
    int wv = tid >> 6;
    int l  = tid & 63;
    int lr = l & 15;
    int lc = l >> 4;

    int bid   = blockIdx.x;
    int it    = bid & 127;
    int b     = (bid >> 7) & 1;
    int split = bid >> 8;

    // zero all of ss (h>=16 region must stay zero; swizzle is a bijection)
    for (int o = tid * 16; o < 512 * 64; o += 256 * 16)
        *(uint4*)(ss + o) = make_uint4(0, 0, 0, 0);

    // Wpre fragment (A of 16x16x32, K padded to 32): row g = lr, k(h) = lc*8+e
    h8v wpre;
    #pragma unroll
    for (int e = 0; e < 8; ++e) {
        int k = lc * 8 + e;
        wpre[e] = (k < 16) ? (f16)(Wpre[lr * 16 + k] * SCALE) : (f16)0.0f;
    }
    // Wpost fragment (A of 16x16x16): row g' = lr, k(g) = lc*4+e
    h4v wpost;
    if (FULL) {
        #pragma unroll
        for (int e = 0; e < 4; ++e) wpost[e] = (f16)Wpost[lr * 16 + lc * 4 + e];
    }

    // Q fragments: wave's heads 4wv..4wv+3, rows it*16..+15
    h8v qf[4][2];
    #pragma unroll
    for (int hh = 0; hh < 4; ++hh)
        #pragma unroll
        for (int ks = 0; ks < 2; ++ks) {
            size_t off = ((((size_t)((b*128 + it)*16 + (wv*4 + hh))*2 + ks)*4 + lc)*16 + lr)*8;
            qf[hh][ks] = *(const h8v*)(Qh + off);
        }

    float zin4[4];
    float zacc[4] = {0.f, 0.f, 0.f, 0.f};
    if (FULL) {
        int g = tid >> 4, i = tid & 15;
        size_t idx = (size_t)(b * 16 + g) * SEQ + it * 16 + i;
        zred[tid] = 1.0f / (Zp[idx] + Zp[65536 + idx]);
    }
    __syncthreads();
    if (FULL) {
        #pragma unroll
        for (int r = 0; r < 4; ++r) zin4[r] = zred[(lc * 4 + r) * 16 + lr];
    }

    f4v pv[4][4];
    if (FULL) {
        #pragma unroll
        for (int gg = 0; gg < 4; ++gg)
            #pragma unroll
            for (int dt = 0; dt < 4; ++dt) pv[gg][dt] = (f4v){0.f, 0.f, 0.f, 0.f};
    }

    int j0beg = split * 1024;
    for (int j0 = j0beg; j0 < j0beg + 1024; j0 += 32) {
        // ---- phase 1: QK^T for wave's 4 heads ----
        f4v qk[4][2];
        #pragma unroll
        for (int hh = 0; hh < 4; ++hh)
            #pragma unroll
            for (int js = 0; js < 2; ++js) qk[hh][js] = (f4v){0.f, 0.f, 0.f, 0.f};
        int jt0 = j0 >> 4;
        #pragma unroll
        for (int hh = 0; hh < 4; ++hh) {
            h8v kf[2][2];
            #pragma unroll
            for (int js = 0; js < 2; ++js)
                #pragma unroll
                for (int ks = 0; ks < 2; ++ks) {
                    size_t off = ((((size_t)((b*128 + jt0 + js)*16 + (wv*4 + hh))*2 + ks)*4 + lc)*16 + lr)*8;
                    kf[js][ks] = *(const h8v*)(Kh + off);
                }
            #pragma unroll
            for (int js = 0; js < 2; ++js)
                #pragma unroll
                for (int ks = 0; ks < 2; ++ks)
                    qk[hh][js] = mfma32(qf[hh][ks], kf[js][ks], qk[hh][js]);
        }
        // S0 -> ss (f16, 4 heads packed per 8B, swizzled). D: row i=lc*4+r, col j'=lr
        #pragma unroll
        for (int js = 0; js < 2; ++js)
            #pragma unroll
            for (int r = 0; r < 4; ++r) {
                int pt = (js * 16 + lr) * 16 + (lc * 4 + r);
                u32 lo = pkh(qk[0][js][r], qk[1][js][r]);
                u32 hi = pkh(qk[2][js][r], qk[3][js][r]);
                *(uint2*)(ss + ssp(pt, wv * 8)) = make_uint2(lo, hi);
            }
        __syncthreads();

        // ---- phase 2: premix MFMA -> exp -> (Z accum | x1/Z -> postmix MFMA -> es) ----
        u32 a2p[4][4];
        #pragma unroll
        for (int tt = 0; tt < 8; ++tt) {
            int t = wv * 8 + tt;          // j within step
            int pt = t * 16 + lr;
            uint2 blo = *(uint2*)(ss + ssp(pt, lc * 16));
            uint2 bhi = *(uint2*)(ss + ssp(pt, lc * 16 + 8));
            union { uint2 u[2]; h8v v; } cv;
            cv.u[0] = blo; cv.u[1] = bhi;
            f4v s1 = mfma32(wpre, cv.v, (f4v){0.f, 0.f, 0.f, 0.f});
            if (!FULL) {
                #pragma unroll
                for (int r = 0; r < 4; ++r) zacc[r] += __expf(s1[r]);
            } else {
                h4v pf;
                #pragma unroll
                for (int r = 0; r < 4; ++r) pf[r] = (f16)(__expf(s1[r]) * zin4[r]);
                f4v a2 = mfma16(wpost, pf, (f4v){0.f, 0.f, 0.f, 0.f});
                #pragma unroll
                for (int r = 0; r < 4; ++r) {
                    u32 v = (u32)__builtin_bit_cast(u16, (f16)a2[r]);
                    if (tt & 1) a2p[r][tt >> 1] |= v << 16;
                    else        a2p[r][tt >> 1]  = v;
                }
            }
        }
        if (FULL) {
            #pragma unroll
            for (int r = 0; r < 4; ++r) {
                int gq = lc * 4 + r;
                int off = (gq * 1024 + lr * 64 + wv * 16) ^ ((lr & 7) << 4);
                *(uint4*)(es + off) = make_uint4(a2p[r][0], a2p[r][1], a2p[r][2], a2p[r][3]);
            }
        }
        __syncthreads();

        // ---- phase 3: PV for wave's 4 output heads ----
        if (FULL) {
            #pragma unroll
            for (int gg = 0; gg < 4; ++gg) {
                int g = wv * 4 + gg;
                h8v af = *(h8v*)(es + ((g * 1024 + lr * 64 + lc * 16) ^ ((lr & 7) << 4)));
                #pragma unroll
                for (int dt = 0; dt < 4; ++dt) {
                    size_t voff = (((((size_t)(b*64 + (j0 >> 5))*16 + g)*4 + dt)*4 + lc)*16 + lr)*8;
                    h8v vf = *(const h8v*)(Vt + voff);
                    pv[gg][dt] = mfma32(af, vf, pv[gg][dt]);
                }
            }
        }
        // next phase-1 writes ss only; phase-2 reads were before the barrier above -> safe
    }

    if (!FULL) {
        #pragma unroll
        for (int r = 0; r < 4; ++r) zred[((lc * 4 + r) * 16 + lr) * 4 + wv] = zacc[r];
        __syncthreads();
        float z = zred[tid * 4 + 0] + zred[tid * 4 + 1] + zred[tid * 4 + 2] + zred[tid * 4 + 3];
        int g = tid >> 4, i = tid & 15;
        Zout[(size_t)split * 65536 + (size_t)(b * 16 + g) * SEQ + it * 16 + i] = z;
    } else {
        float* dst = Octx + (size_t)split * 4194304;
        #pragma unroll
        for (int gg = 0; gg < 4; ++gg)
            #pragma unroll
            for (int dt = 0; dt < 4; ++dt)
                #pragma unroll
                for (int r = 0; r < 4; ++r) {
                    int row = it * 16 + lc * 4 + r;
                    int col = (wv * 4 + gg) * 64 + dt * 16 + lr;
                    dst[(size_t)(b * SEQ + row) * DMODEL + col] = pv[gg][dt][r];
                }
    }
}

// ---------------------------------------------------------------------------
extern "C" void kernel_launch(void* const* d_in, const int* in_sizes, int n_in,
                              void* d_out, int out_size, void* d_ws, size_t ws_size,
                              hipStream_t stream)
{
    const float* x     = (const float*)d_in[0];
    const float* Wqkv  = (const float*)d_in[1];
    const float* bqkv  = (const float*)d_in[2];
    const float* Wpre  = (const float*)d_in[3];
    const float* Wpost = (const float*)d_in[4];
    const float* Wout  = (const float*)d_in[5];
    const float* bout  = (const float*)d_in[6];
    float* out = (float*)d_out;

    float* ws  = (float*)d_ws;
    float* Qb  = ws;                    // [4096][1024] fp32; later CTXa (split 0)
    float* Kb  = ws + 4194304;          // [4096][1024] fp32; later CTXb (split 1)
    float* Vb  = ws + 8388608;          // [4096][1024] fp32
    f16*   Qh  = (f16*)(ws + 12582912); // 4096*1024 f16 packed
    f16*   Kh  = (f16*)(ws + 14680064);
    f16*   Vt  = (f16*)(ws + 16777216);
    float* Zp  = ws + 18874368;         // [2 splits][2*16*2048]

    dim3 blk(256);
    gemm_bias_kernel<<<dim3(48, 64), blk, 0, stream>>>(x, nullptr, Wqkv, bqkv, Qb, Kb, Vb, 1024, 0);
    pack_qk_kernel<<<2048, blk, 0, stream>>>(Qb, Kb, Qh, Kh);
    pack_v_kernel<<<2048, blk, 0, stream>>>(Vb, Vt);
    attn_core<0><<<512, blk, 0, stream>>>(Qh, Kh, Vt, Wpre, Wpost, nullptr, Zp, nullptr);
    attn_core<1><<<512, blk, 0, stream>>>(Qh, Kh, Vt, Wpre, Wpost, Zp, nullptr, ws);
    gemm_bias_kernel<<<dim3(16, 64), blk, 0, stream>>>(Qb, Kb, Wout, bout, out, nullptr, nullptr, 1024, 1);
}

// Round 4
// 300.487 us; speedup vs baseline: 11.6966x; 2.4367x over previous
//
#include <hip/hip_runtime.h>
#include <cstddef>
#include <cstdint>

#define SEQ    2048
#define DMODEL 1024
#define NHEAD  16
#define HDIM   64
#define SCALE  0.125f

typedef _Float16 f16;
typedef unsigned short u16;
typedef unsigned int   u32;
typedef __attribute__((ext_vector_type(8))) _Float16 h8v;
typedef __attribute__((ext_vector_type(4))) _Float16 h4v;
typedef __attribute__((ext_vector_type(4))) float    f4v;

__device__ __forceinline__ u32 pkh(float a, float b) {
    u16 x = __builtin_bit_cast(u16, (f16)a);
    u16 y = __builtin_bit_cast(u16, (f16)b);
    return (u32)x | ((u32)y << 16);
}

__device__ __forceinline__ f4v mfma32(h8v a, h8v b, f4v c) {
    return __builtin_amdgcn_mfma_f32_16x16x32_f16(a, b, c, 0, 0, 0);
}
__device__ __forceinline__ f4v mfma16(h4v a, h4v b, f4v c) {
    return __builtin_amdgcn_mfma_f32_16x16x16f16(a, b, c, 0, 0, 0);
}

// swizzled byte address into attn ss buffer
__device__ __forceinline__ int ssp(int pt, int off) {
    return (pt*64 + off) ^ (((pt>>4)&15)<<3) ^ ((pt&12)<<1);
}

// ---------------------------------------------------------------------------
// Convert x, Wqkv, Wout (fp32) -> f16 row-major copies.
// ---------------------------------------------------------------------------
__global__ __launch_bounds__(256)
void cvt_f16_kernel(const float* __restrict__ x, const float* __restrict__ Wqkv,
                    const float* __restrict__ Wout,
                    f16* __restrict__ Xh, f16* __restrict__ Wqh, f16* __restrict__ Woh)
{
    size_t i = ((size_t)blockIdx.x * 256 + threadIdx.x) * 8;
    const float* src; f16* dst; size_t off;
    if (i < 4194304)      { src = x;    dst = Xh;  off = i; }
    else if (i < 7340032) { src = Wqkv; dst = Wqh; off = i - 4194304; }
    else                  { src = Wout; dst = Woh; off = i - 7340032; }
    float4 a = *(const float4*)&src[off];
    float4 b = *(const float4*)&src[off + 4];
    uint4 o;
    o.x = pkh(a.x, a.y); o.y = pkh(a.z, a.w);
    o.z = pkh(b.x, b.y); o.w = pkh(b.z, b.w);
    *(uint4*)&dst[off] = o;
}

// ---------------------------------------------------------------------------
// f16 MFMA GEMM: C = A @ B^T + bias. A:[M x K] f16 rm, B:[N x K] f16 rm.
// 128x128 tile, BK=32, 4 waves, reg-staged LDS with slot-XOR swizzle.
// mode 0: store f16. mode 1: store fp32.
// ---------------------------------------------------------------------------
__global__ __launch_bounds__(256)
void gemm_f16_kernel(const f16* __restrict__ A, const f16* __restrict__ B,
                     const float* __restrict__ bias, void* __restrict__ Cout,
                     int N, int K, int mode)
{
    __shared__ __align__(16) char Asb[8192];
    __shared__ __align__(16) char Bsb[8192];
    int tid = threadIdx.x;
    int w = tid >> 6, l = tid & 63, lr = l & 15, lc = l >> 4;
    int row0 = blockIdx.y * 128, col0 = blockIdx.x * 128;
    int wr = (w >> 1) * 64, wc = (w & 1) * 64;

    f4v acc[4][4];
    #pragma unroll
    for (int m = 0; m < 4; ++m)
        #pragma unroll
        for (int n = 0; n < 4; ++n) acc[m][n] = (f4v){0.f, 0.f, 0.f, 0.f};

    // slot ids: s = tid + 256*i, i in {0,1}; row = s>>2, ks = s&3
    int r0 = tid >> 2, k0s = tid & 3;
    int r1 = (tid + 256) >> 2, k1s = tid & 3;

    uint4 ra0, ra1, rb0, rb1;
    ra0 = *(const uint4*)&A[(size_t)(row0 + r0) * K + k0s * 8];
    ra1 = *(const uint4*)&A[(size_t)(row0 + r1) * K + k1s * 8];
    rb0 = *(const uint4*)&B[(size_t)(col0 + r0) * K + k0s * 8];
    rb1 = *(const uint4*)&B[(size_t)(col0 + r1) * K + k1s * 8];

    int NT = K >> 5;
    for (int kt = 0; kt < NT; ++kt) {
        *(uint4*)(Asb + r0 * 64 + ((k0s ^ (r0 & 3)) << 4)) = ra0;
        *(uint4*)(Asb + r1 * 64 + ((k1s ^ (r1 & 3)) << 4)) = ra1;
        *(uint4*)(Bsb + r0 * 64 + ((k0s ^ (r0 & 3)) << 4)) = rb0;
        *(uint4*)(Bsb + r1 * 64 + ((k1s ^ (r1 & 3)) << 4)) = rb1;
        if (kt + 1 < NT) {
            int kk = (kt + 1) * 32;
            ra0 = *(const uint4*)&A[(size_t)(row0 + r0) * K + kk + k0s * 8];
            ra1 = *(const uint4*)&A[(size_t)(row0 + r1) * K + kk + k1s * 8];
            rb0 = *(const uint4*)&B[(size_t)(col0 + r0) * K + kk + k0s * 8];
            rb1 = *(const uint4*)&B[(size_t)(col0 + r1) * K + kk + k1s * 8];
        }
        __syncthreads();
        h8v af[4], bf[4];
        #pragma unroll
        for (int m = 0; m < 4; ++m) {
            int row = wr + m * 16 + lr;
            af[m] = *(h8v*)(Asb + row * 64 + ((lc ^ (row & 3)) << 4));
        }
        #pragma unroll
        for (int n = 0; n < 4; ++n) {
            int col = wc + n * 16 + lr;
            bf[n] = *(h8v*)(Bsb + col * 64 + ((lc ^ (col & 3)) << 4));
        }
        #pragma unroll
        for (int m = 0; m < 4; ++m)
            #pragma unroll
            for (int n = 0; n < 4; ++n)
                acc[m][n] = mfma32(af[m], bf[n], acc[m][n]);
        __syncthreads();
    }

    #pragma unroll
    for (int m = 0; m < 4; ++m)
        #pragma unroll
        for (int r = 0; r < 4; ++r) {
            int row = row0 + wr + m * 16 + lc * 4 + r;
            #pragma unroll
            for (int n = 0; n < 4; ++n) {
                int col = col0 + wc + n * 16 + lr;
                float v = acc[m][n][r] + bias[col];
                if (mode == 0) ((f16*)Cout)[(size_t)row * N + col] = (f16)v;
                else           ((float*)Cout)[(size_t)row * N + col] = v;
            }
        }
}

// ---------------------------------------------------------------------------
// Pack Q,K (with RoPE) from f16 QKV [row][3072] into f16 MFMA frag layout.
// ---------------------------------------------------------------------------
__global__ __launch_bounds__(256)
void pack_qk_kernel(const f16* __restrict__ QKVh, f16* __restrict__ Qh, f16* __restrict__ Kh)
{
    int gid = blockIdx.x * 256 + threadIdx.x;
    int i     = gid & 15;
    int t8    = (gid >> 4) & 3;
    int h     = (gid >> 6) & 15;
    int rh    = (gid >> 10) & 255;
    int which = (gid >> 18) & 1;
    int row = rh * 16 + i;
    int pos = row & (SEQ - 1);
    int b   = row >> 11;
    f16* dst = which ? Kh : Qh;

    h8v x1 = *(const h8v*)&QKVh[(size_t)row * 3072 + which * 1024 + h * 64 + t8 * 8];
    h8v x2 = *(const h8v*)&QKVh[(size_t)row * 3072 + which * 1024 + h * 64 + t8 * 8 + 32];

    float y1[8], y2[8];
    #pragma unroll
    for (int e = 0; e < 8; ++e) {
        int t = t8 * 8 + e;
        float inv = exp2f((float)(-2 * t) * (0.015625f * 13.287712379549449f)); // log2(10000)
        float ang = (float)pos * inv;
        float c, s;
        sincosf(ang, &s, &c);
        float a1 = (float)x1[e], a2 = (float)x2[e];
        y1[e] = a1 * c - a2 * s;
        y2[e] = a1 * s + a2 * c;
    }
    int it = pos >> 4;
    size_t b0 = (((((size_t)(b*128 + it)*16 + h)*2 + 0)*4 + t8)*16 + i)*8;
    size_t b1 = (((((size_t)(b*128 + it)*16 + h)*2 + 1)*4 + t8)*16 + i)*8;
    uint4 o0, o1;
    o0.x = pkh(y1[0], y1[1]); o0.y = pkh(y1[2], y1[3]);
    o0.z = pkh(y1[4], y1[5]); o0.w = pkh(y1[6], y1[7]);
    o1.x = pkh(y2[0], y2[1]); o1.y = pkh(y2[2], y2[3]);
    o1.z = pkh(y2[4], y2[5]); o1.w = pkh(y2[6], y2[7]);
    *(uint4*)(dst + b0) = o0;
    *(uint4*)(dst + b1) = o1;
}

// ---------------------------------------------------------------------------
// Pack V from f16 QKV [row][3072] (cols 2048..3071) into PV B-frag layout.
// ---------------------------------------------------------------------------
__global__ __launch_bounds__(256)
void pack_v_kernel(const f16* __restrict__ QKVh, f16* __restrict__ Vt)
{
    int gid = blockIdx.x * 256 + threadIdx.x;
    int dd = gid & 15;
    int jc = (gid >> 4) & 3;
    int dt = (gid >> 6) & 3;
    int g  = (gid >> 8) & 15;
    int jt = (gid >> 12) & 63;
    int b  = (gid >> 18) & 1;
    int d = g * 64 + dt * 16 + dd;
    f16 v[8];
    #pragma unroll
    for (int e = 0; e < 8; ++e) {
        int j = jt * 32 + jc * 8 + e;
        v[e] = QKVh[(size_t)(b * SEQ + j) * 3072 + 2048 + d];
    }
    size_t off = ((((((size_t)b*64 + jt)*16 + g)*4 + dt)*4 + jc)*16 + dd)*8;
    uint4 o;
    o.x = pkh((float)v[0], (float)v[1]); o.y = pkh((float)v[2], (float)v[3]);
    o.z = pkh((float)v[4], (float)v[5]); o.w = pkh((float)v[6], (float)v[7]);
    *(uint4*)(Vt + off) = o;
}

// ---------------------------------------------------------------------------
// Sum attention split partials (fp32) -> f16 CTX [4096][1024].
// ---------------------------------------------------------------------------
__global__ __launch_bounds__(256)
void pack_ctx_kernel(const float* __restrict__ Ca, const float* __restrict__ Cb,
                     f16* __restrict__ Ch)
{
    size_t i = ((size_t)blockIdx.x * 256 + threadIdx.x) * 8;
    float4 a0 = *(const float4*)&Ca[i];
    float4 a1 = *(const float4*)&Ca[i + 4];
    float4 b0 = *(const float4*)&Cb[i];
    float4 b1 = *(const float4*)&Cb[i + 4];
    uint4 o;
    o.x = pkh(a0.x + b0.x, a0.y + b0.y);
    o.y = pkh(a0.z + b0.z, a0.w + b0.w);
    o.z = pkh(a1.x + b1.x, a1.y + b1.y);
    o.w = pkh(a1.z + b1.z, a1.w + b1.w);
    *(uint4*)&Ch[i] = o;
}

// ---------------------------------------------------------------------------
// MFMA talking-heads attention core.
// ---------------------------------------------------------------------------
template<int FULL>
__global__ __launch_bounds__(256, 2)
void attn_core(const f16* __restrict__ Qh, const f16* __restrict__ Kh,
               const f16* __restrict__ Vt, const float* __restrict__ Wpre,
               const float* __restrict__ Wpost, const float* __restrict__ Zp,
               float* __restrict__ Zout, float* __restrict__ Octx)
{
    __shared__ __align__(16) char ss[512 * 64];
    __shared__ __align__(16) char es[FULL ? 16 * 1024 : 16];
    __shared__ float zred[1024];

    int tid = threadIdx.x;
    int wv = tid >> 6;
    int l  = tid & 63;
    int lr = l & 15;
    int lc = l >> 4;

    int bid   = blockIdx.x;
    int it    = bid & 127;
    int b     = (bid >> 7) & 1;
    int split = bid >> 8;

    for (int o = tid * 16; o < 512 * 64; o += 256 * 16)
        *(uint4*)(ss + o) = make_uint4(0, 0, 0, 0);

    h8v wpre;
    #pragma unroll
    for (int e = 0; e < 8; ++e) {
        int k = lc * 8 + e;
        wpre[e] = (k < 16) ? (f16)(Wpre[lr * 16 + k] * SCALE) : (f16)0.0f;
    }
    h4v wpost;
    if (FULL) {
        #pragma unroll
        for (int e = 0; e < 4; ++e) wpost[e] = (f16)Wpost[lr * 16 + lc * 4 + e];
    }

    h8v qf[4][2];
    #pragma unroll
    for (int hh = 0; hh < 4; ++hh)
        #pragma unroll
        for (int ks = 0; ks < 2; ++ks) {
            size_t off = ((((size_t)((b*128 + it)*16 + (wv*4 + hh))*2 + ks)*4 + lc)*16 + lr)*8;
            qf[hh][ks] = *(const h8v*)(Qh + off);
        }

    float zin4[4];
    float zacc[4] = {0.f, 0.f, 0.f, 0.f};
    if (FULL) {
        int g = tid >> 4, i = tid & 15;
        size_t idx = (size_t)(b * 16 + g) * SEQ + it * 16 + i;
        zred[tid] = 1.0f / (Zp[idx] + Zp[65536 + idx]);
    }
    __syncthreads();
    if (FULL) {
        #pragma unroll
        for (int r = 0; r < 4; ++r) zin4[r] = zred[(lc * 4 + r) * 16 + lr];
    }

    f4v pv[4][4];
    if (FULL) {
        #pragma unroll
        for (int gg = 0; gg < 4; ++gg)
            #pragma unroll
            for (int dt = 0; dt < 4; ++dt) pv[gg][dt] = (f4v){0.f, 0.f, 0.f, 0.f};
    }

    int j0beg = split * 1024;
    for (int j0 = j0beg; j0 < j0beg + 1024; j0 += 32) {
        f4v qk[4][2];
        #pragma unroll
        for (int hh = 0; hh < 4; ++hh)
            #pragma unroll
            for (int js = 0; js < 2; ++js) qk[hh][js] = (f4v){0.f, 0.f, 0.f, 0.f};
        int jt0 = j0 >> 4;
        #pragma unroll
        for (int hh = 0; hh < 4; ++hh) {
            h8v kf[2][2];
            #pragma unroll
            for (int js = 0; js < 2; ++js)
                #pragma unroll
                for (int ks = 0; ks < 2; ++ks) {
                    size_t off = ((((size_t)((b*128 + jt0 + js)*16 + (wv*4 + hh))*2 + ks)*4 + lc)*16 + lr)*8;
                    kf[js][ks] = *(const h8v*)(Kh + off);
                }
            #pragma unroll
            for (int js = 0; js < 2; ++js)
                #pragma unroll
                for (int ks = 0; ks < 2; ++ks)
                    qk[hh][js] = mfma32(qf[hh][ks], kf[js][ks], qk[hh][js]);
        }
        #pragma unroll
        for (int js = 0; js < 2; ++js)
            #pragma unroll
            for (int r = 0; r < 4; ++r) {
                int pt = (js * 16 + lr) * 16 + (lc * 4 + r);
                u32 lo = pkh(qk[0][js][r], qk[1][js][r]);
                u32 hi = pkh(qk[2][js][r], qk[3][js][r]);
                *(uint2*)(ss + ssp(pt, wv * 8)) = make_uint2(lo, hi);
            }
        __syncthreads();

        u32 a2p[4][4];
        #pragma unroll
        for (int tt = 0; tt < 8; ++tt) {
            int t = wv * 8 + tt;
            int pt = t * 16 + lr;
            uint2 blo = *(uint2*)(ss + ssp(pt, lc * 16));
            uint2 bhi = *(uint2*)(ss + ssp(pt, lc * 16 + 8));
            union { uint2 u[2]; h8v v; } cv;
            cv.u[0] = blo; cv.u[1] = bhi;
            f4v s1 = mfma32(wpre, cv.v, (f4v){0.f, 0.f, 0.f, 0.f});
            if (!FULL) {
                #pragma unroll
                for (int r = 0; r < 4; ++r) zacc[r] += __expf(s1[r]);
            } else {
                h4v pf;
                #pragma unroll
                for (int r = 0; r < 4; ++r) pf[r] = (f16)(__expf(s1[r]) * zin4[r]);
                f4v a2 = mfma16(wpost, pf, (f4v){0.f, 0.f, 0.f, 0.f});
                #pragma unroll
                for (int r = 0; r < 4; ++r) {
                    u32 v = (u32)__builtin_bit_cast(u16, (f16)a2[r]);
                    if (tt & 1) a2p[r][tt >> 1] |= v << 16;
                    else        a2p[r][tt >> 1]  = v;
                }
            }
        }
        if (FULL) {
            #pragma unroll
            for (int r = 0; r < 4; ++r) {
                int gq = lc * 4 + r;
                int off = (gq * 1024 + lr * 64 + wv * 16) ^ ((lr & 7) << 4);
                *(uint4*)(es + off) = make_uint4(a2p[r][0], a2p[r][1], a2p[r][2], a2p[r][3]);
            }
        }
        __syncthreads();

        if (FULL) {
            #pragma unroll
            for (int gg = 0; gg < 4; ++gg) {
                int g = wv * 4 + gg;
                h8v af = *(h8v*)(es + ((g * 1024 + lr * 64 + lc * 16) ^ ((lr & 7) << 4)));
                #pragma unroll
                for (int dt = 0; dt < 4; ++dt) {
                    size_t voff = (((((size_t)(b*64 + (j0 >> 5))*16 + g)*4 + dt)*4 + lc)*16 + lr)*8;
                    h8v vf = *(const h8v*)(Vt + voff);
                    pv[gg][dt] = mfma32(af, vf, pv[gg][dt]);
                }
            }
        }
    }

    if (!FULL) {
        #pragma unroll
        for (int r = 0; r < 4; ++r) zred[((lc * 4 + r) * 16 + lr) * 4 + wv] = zacc[r];
        __syncthreads();
        float z = zred[tid * 4 + 0] + zred[tid * 4 + 1] + zred[tid * 4 + 2] + zred[tid * 4 + 3];
        int g = tid >> 4, i = tid & 15;
        Zout[(size_t)split * 65536 + (size_t)(b * 16 + g) * SEQ + it * 16 + i] = z;
    } else {
        float* dst = Octx + (size_t)split * 4194304;
        #pragma unroll
        for (int gg = 0; gg < 4; ++gg)
            #pragma unroll
            for (int dt = 0; dt < 4; ++dt)
                #pragma unroll
                for (int r = 0; r < 4; ++r) {
                    int row = it * 16 + lc * 4 + r;
                    int col = (wv * 4 + gg) * 64 + dt * 16 + lr;
                    dst[(size_t)(b * SEQ + row) * DMODEL + col] = pv[gg][dt][r];
                }
    }
}

// ---------------------------------------------------------------------------
extern "C" void kernel_launch(void* const* d_in, const int* in_sizes, int n_in,
                              void* d_out, int out_size, void* d_ws, size_t ws_size,
                              hipStream_t stream)
{
    const float* x     = (const float*)d_in[0];
    const float* Wqkv  = (const float*)d_in[1];
    const float* bqkv  = (const float*)d_in[2];
    const float* Wpre  = (const float*)d_in[3];
    const float* Wpost = (const float*)d_in[4];
    const float* Wout  = (const float*)d_in[5];
    const float* bout  = (const float*)d_in[6];
    float* out = (float*)d_out;

    float* ws = (float*)d_ws;
    // float offsets (1M = 1048576)
    f16*   QKVh = (f16*)(ws);                  // 6.29M f16 in [0, 4M floats); later CTXa/CTXb overlay
    float* CTXa = ws;                          // [0, 4M)  fp32  (after packs done)
    float* CTXb = ws + 4194304;                // [4M, 8M) fp32
    f16*   Xh   = (f16*)(ws + 8388608);        // [8M, 10M)
    f16*   Wqh  = (f16*)(ws + 10485760);       // [10M, 11.5M)
    f16*   Woh  = (f16*)(ws + 12058624);       // [11.5M, 12M)
    f16*   Qh   = (f16*)(ws + 12582912);       // [12M, 14M)
    f16*   Kh   = (f16*)(ws + 14680064);       // [14M, 16M)
    f16*   Vt   = (f16*)(ws + 16777216);       // [16M, 18M)
    f16*   Ch   = (f16*)(ws + 18874368);       // [18M, 19M)
    float* Zp   = ws + 19922944;               // [19M, +131072)

    dim3 blk(256);
    cvt_f16_kernel<<<4096, blk, 0, stream>>>(x, Wqkv, Wout, Xh, Wqh, Woh);
    gemm_f16_kernel<<<dim3(24, 32), blk, 0, stream>>>(Xh, Wqh, bqkv, (void*)QKVh, 3072, 1024, 0);
    pack_qk_kernel<<<2048, blk, 0, stream>>>(QKVh, Qh, Kh);
    pack_v_kernel<<<2048, blk, 0, stream>>>(QKVh, Vt);
    attn_core<0><<<512, blk, 0, stream>>>(Qh, Kh, Vt, Wpre, Wpost, nullptr, Zp, nullptr);
    attn_core<1><<<512, blk, 0, stream>>>(Qh, Kh, Vt, Wpre, Wpost, Zp, nullptr, ws);
    pack_ctx_kernel<<<2048, blk, 0, stream>>>(CTXa, CTXb, Ch);
    gemm_f16_kernel<<<dim3(8, 32), blk, 0, stream>>>(Ch, Woh, bout, (void*)out, 1024, 1024, 1);
}